// Round 3
// baseline (580.526 us; speedup 1.0000x reference)
//
#include <hip/hip_runtime.h>
#include <hip/hip_bf16.h>

#define S_DIM 4096
#define B_DIM 16
#define E_DIM 1024
#define D_DIM 1024
#define A_DIM 512
#define M_DIM (S_DIM * B_DIM)
#define BK 64                 // k-step (128 B bf16 rows -> clean XOR swizzle)
#define NKS (E_DIM / BK)      // 16
#define MT 128                // rows per block
#define CTX_CH 32             // s-chunks for context pass

typedef __bf16 bf16x8 __attribute__((ext_vector_type(8)));
typedef __bf16 bf16x2 __attribute__((ext_vector_type(2)));
typedef float f32x4 __attribute__((ext_vector_type(4)));
typedef unsigned short u16;

__device__ __forceinline__ unsigned pack2(float a, float b) {
    bf16x2 h;
    h[0] = (__bf16)a;          // native v_cvt (RNE), compiler pairs into cvt_pk
    h[1] = (__bf16)b;
    return __builtin_bit_cast(unsigned, h);
}

// We [E][A] f32 -> WeT [A][E] bf16 (plain row-major; B-frags read direct from L2)
__global__ void k_prep_we(const float* __restrict__ We, u16* __restrict__ WeT) {
    __shared__ float tile[32][33];
    const int e0 = blockIdx.x * 32;
    const int a0 = blockIdx.y * 32;
    const int tx = threadIdx.x, ty = threadIdx.y;   // 32 x 8
#pragma unroll
    for (int i = 0; i < 32; i += 8)
        tile[ty + i][tx] = We[(size_t)(e0 + ty + i) * A_DIM + a0 + tx];
    __syncthreads();
#pragma unroll
    for (int i = 0; i < 32; i += 8) {
        bf16x2 h; h[0] = (__bf16)tile[tx][ty + i]; h[1] = (__bf16)0.f;
        WeT[(size_t)(a0 + ty + i) * E_DIM + e0 + tx] =
            (u16)(__builtin_bit_cast(unsigned, h) & 0xffffu);
    }
}

// comb[b][a] = dec[b,:].Wd[:,a] + bd[a] + be[a]   grid(8,16) x 256
__global__ void k_comb(const float* __restrict__ dec, const float* __restrict__ Wd,
                       const float* __restrict__ bd, const float* __restrict__ be,
                       float* __restrict__ comb) {
    __shared__ float red[4][64];
    const int a0 = blockIdx.x * 64;
    const int b = blockIdx.y;
    const int t = threadIdx.x;
    const int al = t & 63, w = t >> 6;
    float acc = 0.f;
    const float* dp = dec + (size_t)b * D_DIM + w * 256;
    const float* wp = Wd + (size_t)w * 256 * A_DIM + a0 + al;
#pragma unroll 4
    for (int d = 0; d < 256; ++d)
        acc += dp[d] * wp[(size_t)d * A_DIM];
    red[w][al] = acc;
    __syncthreads();
    if (t < 64)
        comb[b * A_DIM + a0 + t] =
            red[0][t] + red[1][t] + red[2][t] + red[3][t] + bd[a0 + t] + be[a0 + t];
}

// scores[b][s] = sum_a tanh(enc@We + comb) * Ws   (bs dropped: softmax-invariant)
// 128 rows x 512 cols per block, BK=64, 8 waves (2 row-groups x 4 col-groups).
// A: f32->bf16 into XOR-swizzled LDS, double-buffered. B: direct global->VGPR (L2-hot).
__global__ __launch_bounds__(512, 2)
void k_scores(const float* __restrict__ enc, const u16* __restrict__ WeT,
              const float* __restrict__ comb, const float* __restrict__ Wsv,
              float* __restrict__ scores) {
    __shared__ __align__(16) u16 As[2][MT * BK];   // 2 x 16 KB
    __shared__ float sred[MT];

    const int tid = threadIdx.x;
    const int lane = tid & 63;
    const int wave = tid >> 6;
    const int wr = wave >> 2;             // 0..1
    const int wc = wave & 3;              // 0..3
    const int l15 = lane & 15, lhi = lane >> 4;
    const int blockRow = blockIdx.x * MT;

    if (tid < MT) sred[tid] = 0.f;

    f32x4 acc[4][8];
#pragma unroll
    for (int mf = 0; mf < 4; ++mf)
#pragma unroll
        for (int nf = 0; nf < 8; ++nf)
            acc[mf][nf] = f32x4{0.f, 0.f, 0.f, 0.f};

    // staging geometry: 1024 16B-chunks (128 rows x 8), 512 threads x 2
    const int sr0 = tid >> 3, sd = tid & 7;

    // initial A stage (ks=0) into As[0]
    float4 pv[4];
#pragma unroll
    for (int h = 0; h < 2; ++h) {
        const int r = sr0 + h * 64;
        const int c = sd ^ (r & 7);
        const float* src = enc + (size_t)(blockRow + r) * E_DIM + c * 8;
        pv[2 * h]     = *reinterpret_cast<const float4*>(src);
        pv[2 * h + 1] = *reinterpret_cast<const float4*>(src + 4);
    }
#pragma unroll
    for (int h = 0; h < 2; ++h) {
        const int r = sr0 + h * 64;
        uint4 hh;
        hh.x = pack2(pv[2 * h].x, pv[2 * h].y);
        hh.y = pack2(pv[2 * h].z, pv[2 * h].w);
        hh.z = pack2(pv[2 * h + 1].x, pv[2 * h + 1].y);
        hh.w = pack2(pv[2 * h + 1].z, pv[2 * h + 1].w);
        *reinterpret_cast<uint4*>((char*)As[0] + r * 128 + sd * 16) = hh;
    }
    __syncthreads();

    const u16* bbase = WeT + (size_t)(wc * 128 + l15) * E_DIM + lhi * 8;

    for (int ks = 0; ks < NKS; ++ks) {
        const int cb = ks & 1;
        const int k0 = ks * BK;
        // issue next A-tile global loads early (consumed after MFMA cluster)
        if (ks + 1 < NKS) {
#pragma unroll
            for (int h = 0; h < 2; ++h) {
                const int r = sr0 + h * 64;
                const int c = sd ^ (r & 7);
                const float* src = enc + (size_t)(blockRow + r) * E_DIM + (k0 + BK) + c * 8;
                pv[2 * h]     = *reinterpret_cast<const float4*>(src);
                pv[2 * h + 1] = *reinterpret_cast<const float4*>(src + 4);
            }
        }
#pragma unroll
        for (int kk = 0; kk < 2; ++kk) {
            bf16x8 af[4];
#pragma unroll
            for (int mf = 0; mf < 4; ++mf) {
                const int rr = wr * 64 + mf * 16 + l15;
                af[mf] = *reinterpret_cast<const bf16x8*>(
                    (const char*)As[cb] + rr * 128 + ((kk * 64 + lhi * 16) ^ ((rr & 7) << 4)));
            }
            bf16x8 bq[8];
#pragma unroll
            for (int nf = 0; nf < 8; ++nf)
                bq[nf] = *reinterpret_cast<const bf16x8*>(
                    bbase + (size_t)nf * 16 * E_DIM + k0 + kk * 32);
#pragma unroll
            for (int nf = 0; nf < 8; ++nf)
#pragma unroll
                for (int mf = 0; mf < 4; ++mf)
                    acc[mf][nf] = __builtin_amdgcn_mfma_f32_16x16x32_bf16(
                        af[mf], bq[nf], acc[mf][nf], 0, 0, 0);
        }
        // convert + write next tile into the other buffer
        if (ks + 1 < NKS) {
#pragma unroll
            for (int h = 0; h < 2; ++h) {
                const int r = sr0 + h * 64;
                uint4 hh;
                hh.x = pack2(pv[2 * h].x, pv[2 * h].y);
                hh.y = pack2(pv[2 * h].z, pv[2 * h].w);
                hh.z = pack2(pv[2 * h + 1].x, pv[2 * h + 1].y);
                hh.w = pack2(pv[2 * h + 1].z, pv[2 * h + 1].w);
                *reinterpret_cast<uint4*>((char*)As[cb ^ 1] + r * 128 + sd * 16) = hh;
            }
        }
        __syncthreads();
    }

    // epilogue: x = acc + comb[b][C]; score_row += tanh(x)*Ws[C]
    float part[4][4] = {};
#pragma unroll
    for (int nf = 0; nf < 8; ++nf) {
        const int C = wc * 128 + nf * 16 + l15;
        const float wsv = Wsv[C];
        float cbv[4];
#pragma unroll
        for (int j = 0; j < 4; ++j)
            cbv[j] = comb[(lhi * 4 + j) * A_DIM + C];   // b = (row)&15 = lhi*4+j
#pragma unroll
        for (int mf = 0; mf < 4; ++mf) {
#pragma unroll
            for (int j = 0; j < 4; ++j) {
                const float x = acc[mf][nf][j] + cbv[j];
                const float e = __expf(-2.f * fabsf(x));
                float th = (1.f - e) / (1.f + e);
                th = (x < 0.f) ? -th : th;
                part[mf][j] += th * wsv;
            }
        }
    }
#pragma unroll
    for (int off = 1; off < 16; off <<= 1)
#pragma unroll
        for (int mf = 0; mf < 4; ++mf)
#pragma unroll
            for (int j = 0; j < 4; ++j)
                part[mf][j] += __shfl_xor(part[mf][j], off, 64);
    if (l15 == 0) {
#pragma unroll
        for (int mf = 0; mf < 4; ++mf)
#pragma unroll
            for (int j = 0; j < 4; ++j)
                atomicAdd(&sred[wr * 64 + mf * 16 + lhi * 4 + j], part[mf][j]);
    }
    __syncthreads();
    if (tid < MT) {
        const int rr = blockRow + tid;
        scores[(size_t)(rr & (B_DIM - 1)) * S_DIM + (rr >> 4)] = sred[tid];
    }
}

__global__ void k_softmax(const float* __restrict__ scores, float* __restrict__ alpha) {
    __shared__ float red[8];
    const int b = blockIdx.x;
    const int tid = threadIdx.x;   // 256
    const float* sc = scores + (size_t)b * S_DIM;
    float m = -1e30f;
    for (int i = tid; i < S_DIM; i += 256) m = fmaxf(m, sc[i]);
#pragma unroll
    for (int off = 32; off; off >>= 1) m = fmaxf(m, __shfl_xor(m, off, 64));
    if ((tid & 63) == 0) red[tid >> 6] = m;
    __syncthreads();
    m = fmaxf(fmaxf(red[0], red[1]), fmaxf(red[2], red[3]));
    float s = 0.f;
    for (int i = tid; i < S_DIM; i += 256) s += __expf(sc[i] - m);
#pragma unroll
    for (int off = 32; off; off >>= 1) s += __shfl_xor(s, off, 64);
    if ((tid & 63) == 0) red[4 + (tid >> 6)] = s;
    __syncthreads();
    const float inv = 1.f / (red[4] + red[5] + red[6] + red[7]);
    float* al = alpha + (size_t)b * S_DIM;
    for (int i = tid; i < S_DIM; i += 256) al[i] = __expf(sc[i] - m) * inv;
}

// stage 1: per-(b, 128-s chunk) weighted partials
__global__ void k_ctx1(const float* __restrict__ enc, const float* __restrict__ alpha,
                       float* __restrict__ partial) {
    const int b = blockIdx.y, ch = blockIdx.x, tid = threadIdx.x;   // 256
    const int s0 = ch * (S_DIM / CTX_CH);
    float4 av = make_float4(0.f, 0.f, 0.f, 0.f);
    const float* al = alpha + (size_t)b * S_DIM + s0;
#pragma unroll 4
    for (int s = 0; s < S_DIM / CTX_CH; ++s) {
        const float a = al[s];
        const float4 v = *reinterpret_cast<const float4*>(
            enc + ((size_t)(s0 + s) * B_DIM + b) * E_DIM + tid * 4);
        av.x += a * v.x; av.y += a * v.y; av.z += a * v.z; av.w += a * v.w;
    }
    reinterpret_cast<float4*>(partial)[((size_t)b * CTX_CH + ch) * 256 + tid] = av;
}

// stage 2: reduce chunks
__global__ void k_ctx2(const float* __restrict__ partial, float* __restrict__ out) {
    const int b = blockIdx.x, tid = threadIdx.x;   // 256
    float4 s = make_float4(0.f, 0.f, 0.f, 0.f);
#pragma unroll
    for (int c = 0; c < CTX_CH; ++c) {
        const float4 v =
            reinterpret_cast<const float4*>(partial)[((size_t)b * CTX_CH + c) * 256 + tid];
        s.x += v.x; s.y += v.y; s.z += v.z; s.w += v.w;
    }
    reinterpret_cast<float4*>(out)[b * 256 + tid] = s;
}

extern "C" void kernel_launch(void* const* d_in, const int* in_sizes, int n_in,
                              void* d_out, int out_size, void* d_ws, size_t ws_size,
                              hipStream_t stream) {
    const float* enc = (const float*)d_in[0];
    const float* dec = (const float*)d_in[1];
    const float* We  = (const float*)d_in[2];
    const float* be  = (const float*)d_in[3];
    const float* Wd  = (const float*)d_in[4];
    const float* bd  = (const float*)d_in[5];
    const float* Ws  = (const float*)d_in[6];
    float* out = (float*)d_out;

    char* ws = (char*)d_ws;
    u16*   WeT     = (u16*)ws;                                  // 1 MB
    float* comb    = (float*)(ws + (1 << 20));                  // 32 KB
    float* scores  = (float*)(ws + (1 << 20) + (32 << 10));     // 256 KB [B][S]
    float* alpha   = (float*)(ws + (1 << 20) + (288 << 10));    // 256 KB
    float* partial = (float*)(ws + (1 << 20) + (544 << 10));    // 2 MB

    hipLaunchKernelGGL(k_prep_we, dim3(E_DIM / 32, A_DIM / 32), dim3(32, 8), 0, stream,
                       We, WeT);
    hipLaunchKernelGGL(k_comb, dim3(A_DIM / 64, B_DIM), dim3(256), 0, stream,
                       dec, Wd, bd, be, comb);
    hipLaunchKernelGGL(k_scores, dim3(M_DIM / MT), dim3(512), 0, stream,
                       enc, WeT, comb, Ws, scores);
    hipLaunchKernelGGL(k_softmax, dim3(B_DIM), dim3(256), 0, stream, scores, alpha);
    hipLaunchKernelGGL(k_ctx1, dim3(CTX_CH, B_DIM), dim3(256), 0, stream,
                       enc, alpha, partial);
    hipLaunchKernelGGL(k_ctx2, dim3(B_DIM), dim3(256), 0, stream, partial, out);
}